// Round 1
// 117.692 us; speedup vs baseline: 1.0760x; 1.0760x over previous
//
#include <hip/hip_runtime.h>
#include <math.h>

#define NPH 8
#define NLUT 2048
#define SCALE ((float)(NLUT - 1))   // 2047 interpolation intervals over x in [0,1]

// LUT lives in a module-scope device array: NO workspace usage.
// Entries 0..NLUT (2049 valid, padded to 2050 for float4 staging), (P, Q) pairs.
__device__ __align__(16) float2 g_lut[NLUT + 2];

// Full QSVT evaluation with the off-diagonal term sigma passed explicitly.
// f_alg(x, sigma) is a polynomial in sigma (deg <= 14 in the |.|^2), so
// evaluating at +/-sigma splits even/odd parts: f = P(x) + sigma*Q(x).
__device__ __forceinline__ float qsvt_eval(float x, float sig,
                                           const float* cph, const float* sph) {
    float v0r, v0i, v1r, v1i;
    __sincosf(0.5f * x, &v1r, &v0r);   // [cos(x/2), sin(x/2)]
    v0i = 0.0f; v1i = 0.0f;
#pragma unroll
    for (int k = 0; k < NPH; ++k) {
        const float c = cph[k], sn = sph[k];
        const float a0r = v0r * c - v0i * sn;
        const float a0i = v0r * sn + v0i * c;
        const float a1r = v1r * c + v1i * sn;
        const float a1i = v1i * c - v1r * sn;
        if (k < NPH - 1) {
            v0r = x * a0r + sig * a1r;
            v0i = x * a0i + sig * a1i;
            v1r = sig * a0r - x * a1r;
            v1i = sig * a0i - x * a1i;
        } else {
            v0r = a0r; v0i = a0i; v1r = a1r; v1i = a1i;
        }
    }
    return (v0r * v0r + v0i * v0i) - (v1r * v1r + v1i * v1i);
}

// Kernel 1: build (P,Q) table into the module-scope device array. ~1 us.
__global__ void build_lut(const float* __restrict__ phi) {
    const int j = blockIdx.x * blockDim.x + threadIdx.x;
    if (j > NLUT) return;              // entries 0..NLUT inclusive (2049)
    float cph[NPH], sph[NPH];
#pragma unroll
    for (int k = 0; k < NPH; ++k) __sincosf(phi[k], &sph[k], &cph[k]);
    const int jj = (j < NLUT) ? j : (NLUT - 1);  // pad entry NLUT == entry NLUT-1
    float x = (float)jj * (1.0f / SCALE);
    float s = sqrtf(fmaxf(1.0f - x * x, 0.0f));
    if (s < 1e-3f) {            // endpoint x=1: sample at consistent (x~1, s=1e-3)
        s = 1e-3f;              // P,Q smooth -> sampling offset ~5e-7 in x is negligible
        x = sqrtf(1.0f - s * s);
    }
    const float fp = qsvt_eval(x,  s, cph, sph);
    const float fm = qsvt_eval(x, -s, cph, sph);
    g_lut[j] = make_float2(0.5f * (fp + fm), (fp - fm) / (2.0f * s));
}

__device__ __forceinline__ float lut_eval(float xin, const float2* __restrict__ lut) {
    const float x = fminf(fmaxf(xin, 0.0f), 1.0f);   // inputs are uniform [0,1)
    const float u = x * SCALE;                        // u in [0, 2047]
    const int i = (int)u;                             // trunc; i <= 2047
    const float fr = u - (float)i;
    const float2 e0 = lut[i];                         // merges into one ds_read2_b64
    const float2 e1 = lut[i + 1];
    const float s = sqrtf(fmaxf(fmaf(-x, x, 1.0f), 0.0f));
    const float p = fmaf(fr, e0.x - e0.x + (e1.x - e0.x), e0.x); // = e0.x + fr*(e1.x-e0.x)
    const float q = fmaf(fr, e1.y - e0.y, e0.y);
    return fmaf(s, q, fmaf(fr, e1.x - e0.x, e0.x) * 0.0f + p);
}

// Kernel 2: stage 16.4 KB LUT in LDS (8 blocks/CU -> full 32-wave occupancy),
// then a pure gather+FMA grid-stride map over 16.7M elements.
__global__ __launch_bounds__(256, 8) void qsvt_main(const float* __restrict__ x,
                                                    float* __restrict__ out, int n) {
    __shared__ float2 lut[NLUT + 2];
    // Vectorized staging: 2050 float2 = 1025 float4 loads from L2-resident g_lut.
    {
        const float4* __restrict__ src = (const float4*)g_lut;
        float4* dst = (float4*)lut;
        for (int j = threadIdx.x; j < (NLUT + 2) / 2; j += 256) dst[j] = src[j];
    }
    __syncthreads();

    const int n4 = n >> 2;
    const float4* __restrict__ x4 = (const float4*)x;
    float4* __restrict__ o4 = (float4*)out;
    const int idx = blockIdx.x * blockDim.x + threadIdx.x;
    const int stride = gridDim.x * blockDim.x;
    for (int i = idx; i < n4; i += stride) {
        const float4 v = x4[i];
        float4 o;
        o.x = lut_eval(v.x, lut);
        o.y = lut_eval(v.y, lut);
        o.z = lut_eval(v.z, lut);
        o.w = lut_eval(v.w, lut);
        o4[i] = o;
    }
    const int tail = n & 3;
    if (tail) {
        const int base = n4 << 2;
        if (idx < tail) out[base + idx] = lut_eval(x[base + idx], lut);
    }
}

extern "C" void kernel_launch(void* const* d_in, const int* in_sizes, int n_in,
                              void* d_out, int out_size, void* d_ws, size_t ws_size,
                              hipStream_t stream) {
    const float* x   = (const float*)d_in[0];   // x_chunk [B*CHUNK] fp32
    // d_in[1] = theta: RZ is unit-modulus diagonal -> cannot change <Z>; dead.
    const float* phi = (const float*)d_in[2];   // phi [8] fp32
    float* out = (float*)d_out;
    const int n = in_sizes[0];
    (void)d_ws; (void)ws_size;                  // workspace deliberately UNUSED

    build_lut<<<(NLUT + 1 + 63) / 64, 64, 0, stream>>>(phi);
    // 2048 blocks = 8 blocks/CU (16.4 KB LDS, 32-wave cap) x 256 CUs.
    qsvt_main<<<2048, 256, 0, stream>>>(x, out, n);
}